// Round 1
// baseline (272.100 us; speedup 1.0000x reference)
//
#include <hip/hip_runtime.h>
#include <hip/hip_bf16.h>

// Problem constants (fixed by the reference)
#define B_  4
#define T_  2048
#define D_  1024
#define H_  16
#define HD_ 64
#define THREE_D (3 * D_)
#define TWO_D   (2 * D_)

typedef short s16x8 __attribute__((ext_vector_type(8)));   // 8 bf16 (4 VGPRs)
typedef float f32x4 __attribute__((ext_vector_type(4)));   // MFMA C/D frag 16x16
typedef float f32x16 __attribute__((ext_vector_type(16))); // MFMA C/D frag 32x32
typedef unsigned int u32x4 __attribute__((ext_vector_type(4)));
typedef unsigned short u16;
typedef unsigned short u16x4 __attribute__((ext_vector_type(4)));

static __device__ __forceinline__ s16x8 load8(const u16* p) {
    return *reinterpret_cast<const s16x8*>(p);
}
static __device__ __forceinline__ u16 f2bf(float f) {
    __hip_bfloat16 h = __float2bfloat16(f);
    return *reinterpret_cast<u16*>(&h);
}
// packed fp32x2 -> bf16x2 (RNE) in one dword; lo in low half
static __device__ __forceinline__ unsigned cvtpk(float lo, float hi) {
    float2 f; f.x = lo; f.y = hi;
    __hip_bfloat162 h = __float22bfloat162_rn(f);
    return *reinterpret_cast<unsigned*>(&h);
}
// v_permlane32_swap_b32: a'[0:31]=a[0:31], a'[32:63]=b[0:31],
//                        b'[0:31]=a[32:63], b'[32:63]=b[32:63]
static __device__ __forceinline__ void swap32(unsigned& a, unsigned& b) {
    asm("v_permlane32_swap_b32 %0, %1" : "+v"(a), "+v"(b));
}

// global -> LDS direct DMA, 16B per lane (m97 ladder step: 517 -> 874 TF)
static __device__ __forceinline__ void gload_lds16(const u16* g, u16* l) {
#if __has_builtin(__builtin_amdgcn_global_load_lds)
    __builtin_amdgcn_global_load_lds(
        (__attribute__((address_space(1))) void*)g,
        (__attribute__((address_space(3))) void*)l, 16, 0, 0);
#else
    *reinterpret_cast<s16x8*>(l) = load8(g);
#endif
}

// ---------------------------------------------------------------------------
// fp32 -> bf16 convert (RNE), 4 elements/thread.
// ---------------------------------------------------------------------------
__global__ __launch_bounds__(256) void cvt_f32_bf16(
    const float* __restrict__ in, u16* __restrict__ out, int n)
{
    const int i = (blockIdx.x * 256 + threadIdx.x) * 4;
    if (i < n) {
        const float4 f = *reinterpret_cast<const float4*>(in + i);
        u16x4 r;
        r.x = f2bf(f.x); r.y = f2bf(f.y); r.z = f2bf(f.z); r.w = f2bf(f.w);
        *reinterpret_cast<u16x4*>(out + i) = r;
    }
}

// ---------------------------------------------------------------------------
// m97-style GEMM, BK=64 as two 32-wide panels. C = A @ Bm^T.
// MODE 0: fp32 out + fp32 bias (projection GEMM).
// MODE 1: QKV GEMM. N=3072. Cols [0,1024) -> Q (scaled by qsc, bf16 into
//         qk[M,2048]); [1024,2048) -> K (bf16 into qk); [2048,3072) -> V,
//         written DIRECTLY TRANSPOSED into vt[(b*16+h)*64+f][T] as packed
//         b64 (4 C-rows = 4 consecutive t). Kills the transpose_v kernel.
// ---------------------------------------------------------------------------
template<int MODE>
__global__ __launch_bounds__(256) void gemm_bt128(
    const u16* __restrict__ A,
    const u16* __restrict__ Bm,
    void* __restrict__ Cv,
    const float* __restrict__ bias,
    int M, int N, int K, int lda, int ldb, int ldc,
    float qsc, u16* __restrict__ vt)
{
    const int ntiles = N >> 7;
    const int mt = blockIdx.x / ntiles;
    const int nt = blockIdx.x % ntiles;
    const int m0 = mt * 128, n0 = nt * 128;
    const int tid  = threadIdx.x;
    const int lane = tid & 63;
    const int l15  = lane & 15;
    const int quad = lane >> 4;
    const int wave = tid >> 6;
    const int wm = (wave >> 1) * 64;   // wave m-offset in tile
    const int wn = (wave & 1) * 64;    // wave n-offset in tile

    __shared__ u16 A_sh[2][128 * 32];  // [panel][row*32 + k], linear chunks
    __shared__ u16 B_sh[2][128 * 32];

    f32x4 acc[4][4] = {};

    // staging per panel: 512 chunks of 16B; thread t handles chunks t, t+256
    const int c0 = tid, c1 = tid + 256;
    const int ar0 = c0 >> 2, as0 = (c0 & 3) * 8;
    const int ar1 = c1 >> 2, as1 = (c1 & 3) * 8;
    const u16* Ag0 = A  + (size_t)(m0 + ar0) * lda + as0;
    const u16* Ag1 = A  + (size_t)(m0 + ar1) * lda + as1;
    const u16* Bg0 = Bm + (size_t)(n0 + ar0) * ldb + as0;
    const u16* Bg1 = Bm + (size_t)(n0 + ar1) * ldb + as1;

    for (int k0 = 0; k0 < K; k0 += 64) {
        __syncthreads();                  // prior iteration's LDS reads done
        #pragma unroll
        for (int p = 0; p < 2; ++p) {
            gload_lds16(Ag0 + k0 + p * 32, &A_sh[p][c0 * 8]);
            gload_lds16(Ag1 + k0 + p * 32, &A_sh[p][c1 * 8]);
            gload_lds16(Bg0 + k0 + p * 32, &B_sh[p][c0 * 8]);
            gload_lds16(Bg1 + k0 + p * 32, &B_sh[p][c1 * 8]);
        }
        __syncthreads();                  // drains vmcnt before barrier

        #pragma unroll
        for (int p = 0; p < 2; ++p) {
            s16x8 a[4], b[4];
            #pragma unroll
            for (int i = 0; i < 4; ++i) {
                a[i] = *reinterpret_cast<const s16x8*>(&A_sh[p][(wm + i * 16 + l15) * 32 + quad * 8]);
                b[i] = *reinterpret_cast<const s16x8*>(&B_sh[p][(wn + i * 16 + l15) * 32 + quad * 8]);
            }
            #pragma unroll
            for (int mi = 0; mi < 4; ++mi)
                #pragma unroll
                for (int ni = 0; ni < 4; ++ni)
                    acc[mi][ni] = __builtin_amdgcn_mfma_f32_16x16x32_bf16(
                        a[mi], b[ni], acc[mi][ni], 0, 0, 0);
        }
    }

    // Epilogue. C/D layout: row = quad*4 + r, col = lane&15
    #pragma unroll
    for (int ni = 0; ni < 4; ++ni) {
        const int col = n0 + wn + ni * 16 + l15;
        if (MODE == 0) {
            const float bv = bias ? bias[col] : 0.0f;
            #pragma unroll
            for (int mi = 0; mi < 4; ++mi) {
                const int row = m0 + wm + mi * 16 + quad * 4;
                #pragma unroll
                for (int r = 0; r < 4; ++r)
                    ((float*)Cv)[(size_t)(row + r) * ldc + col] = acc[mi][ni][r] + bv;
            }
        } else {
            if (col < TWO_D) {               // Q (scaled) or K -> qk buffer
                const float sc = (col < D_) ? qsc : 1.0f;
                #pragma unroll
                for (int mi = 0; mi < 4; ++mi) {
                    const int row = m0 + wm + mi * 16 + quad * 4;
                    #pragma unroll
                    for (int r = 0; r < 4; ++r)
                        ((u16*)Cv)[(size_t)(row + r) * ldc + col] = f2bf(acc[mi][ni][r] * sc);
                }
            } else {                         // V -> transposed vt, packed b64
                const int vc = col - TWO_D;  // h*64 + f
                #pragma unroll
                for (int mi = 0; mi < 4; ++mi) {
                    const int row = m0 + wm + mi * 16 + quad * 4;
                    const int bb = row >> 11, t = row & (T_ - 1);
                    u16x4 pk;
                    #pragma unroll
                    for (int r = 0; r < 4; ++r) pk[r] = f2bf(acc[mi][ni][r]);
                    *reinterpret_cast<u16x4*>(
                        vt + ((size_t)(bb * H_ * HD_) + vc) * T_ + t) = pk;
                }
            }
        }
    }
}

// ---------------------------------------------------------------------------
// Causal flash attention v7: 32x32 MFMA, fully in-register P (T12), XOR-
// swizzled K/V LDS (T2), async gload_lds double-buffer w/ 1 barrier/tile.
//
// Per wave: 32 q-rows (w0..w0+31), KV-tile 64.
//   S^T = mfma_32x32x16(A=K, B=Q): C-layout col=l31=qrow,
//     row(key) = (r&3)+8*(r>>2)+4*half. Lanes l and l+32 hold complementary
//     key-halves of the SAME q-row -> P repack to PV A-frags is 16 cvt_pk +
//     8 v_permlane32_swap per tile, NO LDS round trip (kills the 7.5M
//     bank-conflict cycles + 16 DS ops/tile of v6).
//   PV: O[q][f] = mfma(A=P, B=V^T); rowsum via ones-MFMA on the same bf16
//     P frags (osum C-layout == O C-layout, epilogue normalization exact).
//   K_lds/V_lds: [64][64] bf16 rows of 128B, byte ^= (row&7)<<4 swizzle.
//     gload_lds writes linearly -> swizzle applied to the GLOBAL source
//     column (m173 both-sides pattern); ds_read_b128 applies same XOR ->
//     conflict-free (8 slots x 8 lanes x 16B = min cycles).
// ---------------------------------------------------------------------------
__global__ __launch_bounds__(256) void flash_attn7(
    const u16* __restrict__ qk, const u16* __restrict__ vt,
    u16* __restrict__ out)   // [B*T, D] bf16
{
    const int cls = blockIdx.x >> 6;          // 0..15
    const int bh  = blockIdx.x & 63;
    const int qmap[16] = {15,14,13,12, 8,9,10,11, 7,6,5,4, 0,1,2,3};
    const int qt = qmap[cls];
    const int hh = bh & 15, b = bh >> 4;
    const int q0 = qt * 128;

    __shared__ u16 K_lds[2][64 * 64];      // [buf][key][feat], swizzled
    __shared__ u16 V_lds[2][64 * 64];      // [buf][feat][key], swizzled

    const int tid = threadIdx.x;
    const int wave = tid >> 6, lane = tid & 63;
    const int l31 = lane & 31, half = lane >> 5;
    const int sw = (l31 & 7) << 4;         // read-side XOR (byte units)
    const int w0 = q0 + wave * 32;         // wave's first q-row
    const int qr = w0 + l31;               // this lane's q-row (for masking)

    // Q fragments (B-operand of swapped QK^T): Q[w0+l31][s*16+half*8+j]
    s16x8 qf[4];
    {
        const size_t rowQ = (size_t)(b * T_ + w0 + l31) * TWO_D + hh * HD_;
        #pragma unroll
        for (int s = 0; s < 4; ++s)
            qf[s] = load8(qk + rowQ + s * 16 + half * 8);
    }

    f32x16 o[2] = {};                      // O[q in regs][f = fb*32+l31]
    f32x16 osum = {};                      // rowsum, same reg->q map as o

    s16x8 ones;
    #pragma unroll
    for (int j = 0; j < 8; ++j) ones[j] = (short)0x3F80;   // bf16 1.0

    // staging: 512 chunks of 16B per tile per matrix; thread t -> chunks
    // t, t+256 (rows r0, r0+32). Source column pre-swizzled.
    const int r0 = tid >> 3;               // 0..31
    const int ch = tid & 7;                // 16B chunk within 128B row
    const int scol = ((ch * 16) ^ ((r0 & 7) << 4)) >> 1;   // u16 units
    const u16* Kg = qk + (size_t)(b * T_ + r0) * TWO_D + D_ + hh * HD_ + scol;
    const u16* Vg = vt + (size_t)(bh * HD_ + r0) * T_ + scol;

#define STAGE(bf, kb64) do {                                                  \
        const size_t ko = (size_t)(kb64) * TWO_D;                             \
        gload_lds16(Kg + ko,                       &K_lds[bf][(size_t)tid * 8]);        \
        gload_lds16(Kg + ko + (size_t)32 * TWO_D,  &K_lds[bf][(size_t)(tid + 256) * 8]);\
        gload_lds16(Vg + (kb64),                   &V_lds[bf][(size_t)tid * 8]);        \
        gload_lds16(Vg + (kb64) + (size_t)32 * T_, &V_lds[bf][(size_t)(tid + 256) * 8]);\
    } while (0)

    const int nkt = 2 * qt + 2;
    STAGE(0, 0);                           // prologue prefetch
    int cur = 0;

    for (int kt = 0; kt < nkt; ++kt) {
        const int kbase = kt * 64;
        // __syncthreads drains vmcnt(0) before s_barrier (compiler-emitted):
        // my gload_lds for buf[cur] have landed; everyone else's too after
        // the barrier. Also orders last iter's reads of buf[cur^1] before
        // this iter's overwrite.
        __syncthreads();
        if (kt + 1 < nkt) STAGE(cur ^ 1, (kt + 1) * 64);

        if (kbase <= w0 + 31) {            // wave has unmasked work here
            const char* Kb = (const char*)&K_lds[cur][0];
            const char* Vb = (const char*)&V_lds[cur][0];

            // S^T = K Q^T: D[key][qrow]; key = (r&3)+8*(r>>2)+4*half +32*kb
            f32x16 st[2];
            #pragma unroll
            for (int kb = 0; kb < 2; ++kb) {
                f32x16 acc = {};
                #pragma unroll
                for (int s = 0; s < 4; ++s) {
                    const s16x8 kf = *reinterpret_cast<const s16x8*>(
                        Kb + (kb * 32 + l31) * 128 + ((s * 32 + half * 16) ^ sw));
                    acc = __builtin_amdgcn_mfma_f32_32x32x16_bf16(
                        kf, qf[s], acc, 0, 0, 0);
                }
                st[kb] = acc;
            }

            // P = exp2(S^T), causal mask on diag tiles
            const bool diag = (kbase + 63 > w0);
            float p[2][16];
            #pragma unroll
            for (int kb = 0; kb < 2; ++kb)
                #pragma unroll
                for (int r = 0; r < 16; ++r) {
                    float e = exp2f(st[kb][r]);
                    if (diag) {
                        const int key = kbase + kb * 32 + (r & 3) + 8 * (r >> 2) + 4 * half;
                        if (key > qr) e = 0.0f;
                    }
                    p[kb][r] = e;
                }

            // In-register repack: C-layout -> PV A-frags (keys s*16+half*8+j
            // for q = l31). Per (kb,t): groups g=2t,2t+1 packed, one
            // permlane32_swap pair fills words {0,2} and {1,3} of pa.
            s16x8 pa[4];
            #pragma unroll
            for (int kb = 0; kb < 2; ++kb)
                #pragma unroll
                for (int t = 0; t < 2; ++t) {
                    unsigned a  = cvtpk(p[kb][8 * t + 0], p[kb][8 * t + 1]); // g=2t   d0
                    unsigned bq = cvtpk(p[kb][8 * t + 4], p[kb][8 * t + 5]); // g=2t+1 d0
                    unsigned c  = cvtpk(p[kb][8 * t + 2], p[kb][8 * t + 3]); // g=2t   d1
                    unsigned d  = cvtpk(p[kb][8 * t + 6], p[kb][8 * t + 7]); // g=2t+1 d1
                    swap32(a, bq);         // a -> word0, bq -> word2
                    swap32(c, d);          // c -> word1, d  -> word3
                    u32x4 w; w.x = a; w.y = c; w.z = bq; w.w = d;
                    pa[kb * 2 + t] = __builtin_bit_cast(s16x8, w);
                }

            // O += P V ; rowsum += P (ones-MFMA keeps osum consistent with
            // the exact bf16 P that PV consumes)
            #pragma unroll
            for (int s = 0; s < 4; ++s) {
                osum = __builtin_amdgcn_mfma_f32_32x32x16_bf16(
                    pa[s], ones, osum, 0, 0, 0);
                #pragma unroll
                for (int fb = 0; fb < 2; ++fb) {
                    const s16x8 vb = *reinterpret_cast<const s16x8*>(
                        Vb + (fb * 32 + l31) * 128 + ((s * 32 + half * 16) ^ sw));
                    o[fb] = __builtin_amdgcn_mfma_f32_32x32x16_bf16(
                        pa[s], vb, o[fb], 0, 0, 0);
                }
            }
        }
        cur ^= 1;
    }
#undef STAGE

    // Epilogue: O reg r -> qrow = w0 + (r&3)+8*(r>>2)+4*half, f = fb*32+l31
    #pragma unroll
    for (int r = 0; r < 16; ++r) {
        const int qrow = w0 + (r & 3) + 8 * (r >> 2) + 4 * half;
        const float inv = 1.0f / osum[r];
        const size_t ro = (size_t)(b * T_ + qrow) * D_ + hh * HD_;
        out[ro + l31]      = f2bf(o[0][r] * inv);
        out[ro + 32 + l31] = f2bf(o[1][r] * inv);
    }
}

// ---------------------------------------------------------------------------
extern "C" void kernel_launch(void* const* d_in, const int* in_sizes, int n_in,
                              void* d_out, int out_size, void* d_ws, size_t ws_size,
                              hipStream_t stream)
{
    const float* x     = (const float*)d_in[0];  // [B,T,D]  fp32
    const float* Wqkv  = (const float*)d_in[1];  // [3D,D]   fp32
    const float* Wproj = (const float*)d_in[2];  // [D,D]    fp32
    const float* bproj = (const float*)d_in[3];  // [D]      fp32
    float* out = (float*)d_out;                  // [B,T,D]  fp32

    const int M = B_ * T_;
    const float cs = 0.18033688011f;             // (1/sqrt(64)) * log2(e)

    // Workspace (bf16 = u16). Total 88 MB, no aliasing.
    u16* xb    = (u16*)d_ws;                              // [M, D]       16 MB
    u16* wqkvb = xb    + (size_t)M * D_;                  // [3D, D]       6 MB
    u16* wprob = wqkvb + (size_t)THREE_D * D_;            // [D, D]        2 MB
    u16* qk    = wprob + (size_t)D_ * D_;                 // [M, 2D]      32 MB
    u16* vtb   = qk    + (size_t)M * TWO_D;               // [B*H*64, T]  16 MB
    u16* attn  = vtb   + (size_t)B_ * H_ * HD_ * T_;      // [M, D]       16 MB

    // 0) fp32 -> bf16 converts
    {
        int n;
        n = M * D_;
        cvt_f32_bf16<<<dim3((n / 4 + 255) / 256), 256, 0, stream>>>(x, xb, n);
        n = THREE_D * D_;
        cvt_f32_bf16<<<dim3((n / 4 + 255) / 256), 256, 0, stream>>>(Wqkv, wqkvb, n);
        n = D_ * D_;
        cvt_f32_bf16<<<dim3((n / 4 + 255) / 256), 256, 0, stream>>>(Wproj, wprob, n);
    }

    // 1) qkv GEMM: Q (scaled by cs) and K -> qk[M,2D]; V -> vt transposed
    gemm_bt128<1><<<dim3((M / 128) * (THREE_D / 128)), 256, 0, stream>>>(
        xb, wqkvb, qk, nullptr, M, THREE_D, D_, D_, D_, TWO_D, cs, vtb);

    // 2) causal flash attention (bf16 out)
    flash_attn7<<<dim3(B_ * H_ * (T_ / 128)), 256, 0, stream>>>(qk, vtb, attn);

    // 3) out = attn @ Wproj^T + bproj   (fp32 out)
    gemm_bt128<0><<<dim3((M / 128) * (D_ / 128)), 256, 0, stream>>>(
        attn, wprob, out, bproj, M, D_, D_, D_, D_, D_, 1.0f, nullptr);
}

// Round 3
// 266.071 us; speedup vs baseline: 1.0227x; 1.0227x over previous
//
#include <hip/hip_runtime.h>
#include <hip/hip_bf16.h>

// Problem constants (fixed by the reference)
#define B_  4
#define T_  2048
#define D_  1024
#define H_  16
#define HD_ 64
#define THREE_D (3 * D_)
#define TWO_D   (2 * D_)

typedef short s16x8 __attribute__((ext_vector_type(8)));   // 8 bf16 (4 VGPRs)
typedef short s16x4 __attribute__((ext_vector_type(4)));   // 4 bf16 (2 VGPRs)
typedef float f32x4 __attribute__((ext_vector_type(4)));   // MFMA C/D frag 16x16
typedef unsigned int u32x2 __attribute__((ext_vector_type(2)));
typedef unsigned short u16;
typedef unsigned short u16x4 __attribute__((ext_vector_type(4)));

static __device__ __forceinline__ s16x8 load8(const u16* p) {
    return *reinterpret_cast<const s16x8*>(p);
}
static __device__ __forceinline__ u16 f2bf(float f) {
    __hip_bfloat16 h = __float2bfloat16(f);
    return *reinterpret_cast<u16*>(&h);
}
// packed fp32x2 -> bf16x2 (RNE) in one dword; lo in low half
static __device__ __forceinline__ unsigned cvtpk(float lo, float hi) {
    float2 f; f.x = lo; f.y = hi;
    __hip_bfloat162 h = __float22bfloat162_rn(f);
    return *reinterpret_cast<unsigned*>(&h);
}
// K=16 bf16 MFMA via BUILTIN (v8's inline-asm version bypassed the
// compiler's MFMA hazard recognizer -> missing wait states between the
// cvt_pk VALU writes / ds_read results and the MFMA operand reads -> NaN).
// A/B frags are 4 bf16/lane at k = quad*4+j -- exactly the 16x16 C-frag key
// layout, so P feeds PV with no lane movement at all.
static __device__ __forceinline__ void mfma16(f32x4& d, u16x4 a, u16x4 b) {
#if __has_builtin(__builtin_amdgcn_mfma_f32_16x16x16bf16_1k)
    d = __builtin_amdgcn_mfma_f32_16x16x16bf16_1k(
        __builtin_bit_cast(s16x4, a), __builtin_bit_cast(s16x4, b), d, 0, 0, 0);
#else
    // fallback: raw asm with explicit hazard padding (VALU->MFMA read and
    // MFMA write->VALU read wait states)
    asm volatile("s_nop 1\n\t"
                 "v_mfma_f32_16x16x16_bf16 %0, %1, %2, %0\n\t"
                 "s_nop 7\n\t"
                 "s_nop 3"
                 : "+v"(d) : "v"(a), "v"(b));
#endif
}

// global -> LDS direct DMA, 16B per lane (m97 ladder step: 517 -> 874 TF)
static __device__ __forceinline__ void gload_lds16(const u16* g, u16* l) {
#if __has_builtin(__builtin_amdgcn_global_load_lds)
    __builtin_amdgcn_global_load_lds(
        (__attribute__((address_space(1))) void*)g,
        (__attribute__((address_space(3))) void*)l, 16, 0, 0);
#else
    *reinterpret_cast<s16x8*>(l) = load8(g);
#endif
}

// ---------------------------------------------------------------------------
// fp32 -> bf16 convert (RNE), 4 elements/thread.
// ---------------------------------------------------------------------------
__global__ __launch_bounds__(256) void cvt_f32_bf16(
    const float* __restrict__ in, u16* __restrict__ out, int n)
{
    const int i = (blockIdx.x * 256 + threadIdx.x) * 4;
    if (i < n) {
        const float4 f = *reinterpret_cast<const float4*>(in + i);
        u16x4 r;
        r.x = f2bf(f.x); r.y = f2bf(f.y); r.z = f2bf(f.z); r.w = f2bf(f.w);
        *reinterpret_cast<u16x4*>(out + i) = r;
    }
}

// ---------------------------------------------------------------------------
// m97-style GEMM, BK=64 as two 32-wide panels. C = A @ Bm^T.
// MODE 0: fp32 out + fp32 bias (projection GEMM).
// MODE 1: QKV GEMM. N=3072. Cols [0,1024) -> Q (scaled by qsc, bf16 into
//         qk[M,2048]); [1024,2048) -> K (bf16 into qk); [2048,3072) -> V,
//         written DIRECTLY TRANSPOSED into vt[(b*16+h)*64+f][T] as packed
//         b64 (4 C-rows = 4 consecutive t). Kills the transpose_v kernel.
// ---------------------------------------------------------------------------
template<int MODE>
__global__ __launch_bounds__(256) void gemm_bt128(
    const u16* __restrict__ A,
    const u16* __restrict__ Bm,
    void* __restrict__ Cv,
    const float* __restrict__ bias,
    int M, int N, int K, int lda, int ldb, int ldc,
    float qsc, u16* __restrict__ vt)
{
    const int ntiles = N >> 7;
    const int mt = blockIdx.x / ntiles;
    const int nt = blockIdx.x % ntiles;
    const int m0 = mt * 128, n0 = nt * 128;
    const int tid  = threadIdx.x;
    const int lane = tid & 63;
    const int l15  = lane & 15;
    const int quad = lane >> 4;
    const int wave = tid >> 6;
    const int wm = (wave >> 1) * 64;   // wave m-offset in tile
    const int wn = (wave & 1) * 64;    // wave n-offset in tile

    __shared__ u16 A_sh[2][128 * 32];  // [panel][row*32 + k], linear chunks
    __shared__ u16 B_sh[2][128 * 32];

    f32x4 acc[4][4] = {};

    // staging per panel: 512 chunks of 16B; thread t handles chunks t, t+256
    const int c0 = tid, c1 = tid + 256;
    const int ar0 = c0 >> 2, as0 = (c0 & 3) * 8;
    const int ar1 = c1 >> 2, as1 = (c1 & 3) * 8;
    const u16* Ag0 = A  + (size_t)(m0 + ar0) * lda + as0;
    const u16* Ag1 = A  + (size_t)(m0 + ar1) * lda + as1;
    const u16* Bg0 = Bm + (size_t)(n0 + ar0) * ldb + as0;
    const u16* Bg1 = Bm + (size_t)(n0 + ar1) * ldb + as1;

    for (int k0 = 0; k0 < K; k0 += 64) {
        __syncthreads();                  // prior iteration's LDS reads done
        #pragma unroll
        for (int p = 0; p < 2; ++p) {
            gload_lds16(Ag0 + k0 + p * 32, &A_sh[p][c0 * 8]);
            gload_lds16(Ag1 + k0 + p * 32, &A_sh[p][c1 * 8]);
            gload_lds16(Bg0 + k0 + p * 32, &B_sh[p][c0 * 8]);
            gload_lds16(Bg1 + k0 + p * 32, &B_sh[p][c1 * 8]);
        }
        __syncthreads();                  // drains vmcnt before barrier

        #pragma unroll
        for (int p = 0; p < 2; ++p) {
            s16x8 a[4], b[4];
            #pragma unroll
            for (int i = 0; i < 4; ++i) {
                a[i] = *reinterpret_cast<const s16x8*>(&A_sh[p][(wm + i * 16 + l15) * 32 + quad * 8]);
                b[i] = *reinterpret_cast<const s16x8*>(&B_sh[p][(wn + i * 16 + l15) * 32 + quad * 8]);
            }
            #pragma unroll
            for (int mi = 0; mi < 4; ++mi)
                #pragma unroll
                for (int ni = 0; ni < 4; ++ni)
                    acc[mi][ni] = __builtin_amdgcn_mfma_f32_16x16x32_bf16(
                        a[mi], b[ni], acc[mi][ni], 0, 0, 0);
        }
    }

    // Epilogue. C/D layout: row = quad*4 + r, col = lane&15
    #pragma unroll
    for (int ni = 0; ni < 4; ++ni) {
        const int col = n0 + wn + ni * 16 + l15;
        if (MODE == 0) {
            const float bv = bias ? bias[col] : 0.0f;
            #pragma unroll
            for (int mi = 0; mi < 4; ++mi) {
                const int row = m0 + wm + mi * 16 + quad * 4;
                #pragma unroll
                for (int r = 0; r < 4; ++r)
                    ((float*)Cv)[(size_t)(row + r) * ldc + col] = acc[mi][ni][r] + bv;
            }
        } else {
            if (col < TWO_D) {               // Q (scaled) or K -> qk buffer
                const float sc = (col < D_) ? qsc : 1.0f;
                #pragma unroll
                for (int mi = 0; mi < 4; ++mi) {
                    const int row = m0 + wm + mi * 16 + quad * 4;
                    #pragma unroll
                    for (int r = 0; r < 4; ++r)
                        ((u16*)Cv)[(size_t)(row + r) * ldc + col] = f2bf(acc[mi][ni][r] * sc);
                }
            } else {                         // V -> transposed vt, packed b64
                const int vc = col - TWO_D;  // h*64 + f
                #pragma unroll
                for (int mi = 0; mi < 4; ++mi) {
                    const int row = m0 + wm + mi * 16 + quad * 4;
                    const int bb = row >> 11, t = row & (T_ - 1);
                    u16x4 pk;
                    #pragma unroll
                    for (int r = 0; r < 4; ++r) pk[r] = f2bf(acc[mi][ni][r]);
                    *reinterpret_cast<u16x4*>(
                        vt + ((size_t)(bb * H_ * HD_) + vc) * T_ + t) = pk;
                }
            }
        }
    }
}

// ---------------------------------------------------------------------------
// Causal flash attention v9 = v8 with the MFMA-K16 builtin (hazard-safe).
//
// v6-proven parts kept verbatim: 4 waves x 32 q-rows, KV-tile 64, K/V staged
// in LDS (stride-72 pad, near-conflict-free b128/b64 frag reads), register
// prefetch hides HBM latency across the whole tile, S^T = mfma(A=K, B=Q)
// with shared A/B lane layout, ones-MFMA rowsum, qmap load balance.
//
// In-register P (replaces v6's P_lds round trip): the 16x16x32 C-frag holds
// keys quad*4+{0..3} per lane for q-row l15 -- which is EXACTLY the A-frag
// layout of mfma_f32_16x16x16_bf16 (A[m=l15][k=quad*4+j]). So P = exp2(S^T)
// converts straight into PV A-frags with 2 cvt_pk per C-frag: no ds_write,
// no ds_read, no same-wave write->read lgkm stall, no bank conflicts, no
// lane shuffles. PV and rowsum run as K=16 MFMAs (b64 V_lds B-frags).
// Cost: +~100 MFMA cyc/tile at K=16 half-rate; paid for by deleting the
// dominant DS + pack-VALU + conflict item (7.57M conflict cycles in v6).
// ---------------------------------------------------------------------------
__global__ __launch_bounds__(256) void flash_attn9(
    const u16* __restrict__ qk, const u16* __restrict__ vt,
    u16* __restrict__ out)   // [B*T, D] bf16
{
    const int cls = blockIdx.x >> 6;          // 0..15
    const int bh  = blockIdx.x & 63;
    const int qmap[16] = {15,14,13,12, 8,9,10,11, 7,6,5,4, 0,1,2,3};
    const int qt = qmap[cls];
    const int h = bh & 15, b = bh >> 4;
    const int q0 = qt * 128;

    __shared__ u16 K_lds[64 * 72];         // [key][feat], stride 72
    __shared__ u16 V_lds[64 * 72];         // [feat][key], stride 72

    const int tid = threadIdx.x;
    const int wave = tid >> 6, lane = tid & 63;
    const int l15 = lane & 15, quad = lane >> 4;

    const int w0 = q0 + wave * 32;         // wave's first q-row

    // Q fragments: 2 m-tiles x 2 k-steps (pre-scaled by cs in GEMM1)
    s16x8 qf[2][2];
    #pragma unroll
    for (int mi = 0; mi < 2; ++mi) {
        const size_t rowQ = (size_t)(b * T_ + w0 + mi * 16 + l15) * TWO_D + h * HD_;
        qf[mi][0] = load8(qk + rowQ + quad * 8);
        qf[mi][1] = load8(qk + rowQ + 32 + quad * 8);
    }

    f32x4 o[2][4] = {};
    f32x4 osum[2] = {};

    u16x4 ones4;
    #pragma unroll
    for (int j = 0; j < 4; ++j) ones4[j] = 0x3F80;   // bf16 1.0

    // staging: thread covers K rows r0,r0+32 and V feats r0,r0+32, 16B each
    const int r0 = tid >> 3;               // 0..31
    const int s0 = (tid & 7) * 8;          // u16 offset of 16B chunk
    const u16* Kg0 = qk + (size_t)(b * T_ + r0)      * TWO_D + D_ + h * HD_ + s0;
    const u16* Kg1 = qk + (size_t)(b * T_ + r0 + 32) * TWO_D + D_ + h * HD_ + s0;
    const u16* Vg0 = vt + (size_t)(bh * HD_ + r0)      * T_ + s0;
    const u16* Vg1 = vt + (size_t)(bh * HD_ + r0 + 32) * T_ + s0;

    // prefetch tile 0
    s16x8 pk0 = load8(Kg0);
    s16x8 pk1 = load8(Kg1);
    s16x8 pv0 = load8(Vg0);
    s16x8 pv1 = load8(Vg1);

    const int nkt = 2 * qt + 2;
    for (int kt = 0; kt < nkt; ++kt) {
        const int kbase = kt * 64;
        __syncthreads();                   // prior tile's LDS reads done
        *reinterpret_cast<s16x8*>(&K_lds[r0 * 72 + s0])        = pk0;
        *reinterpret_cast<s16x8*>(&K_lds[(r0 + 32) * 72 + s0]) = pk1;
        *reinterpret_cast<s16x8*>(&V_lds[r0 * 72 + s0])        = pv0;
        *reinterpret_cast<s16x8*>(&V_lds[(r0 + 32) * 72 + s0]) = pv1;
        __syncthreads();

        if (kt + 1 < nkt) {                // prefetch next tile (latency
            const int nb = kbase + 64;     //  hidden under this tile's math)
            pk0 = load8(Kg0 + (size_t)nb * TWO_D);
            pk1 = load8(Kg1 + (size_t)nb * TWO_D);
            pv0 = load8(Vg0 + nb);
            pv1 = load8(Vg1 + nb);
        }

        if (kbase <= w0 + 31) {            // wave has unmasked work here
            // S^T = K Q^T : D[m=key][n=qrow]; kf as A, qf as B (same regs)
            f32x4 st[2][4];
            #pragma unroll
            for (int n = 0; n < 4; ++n) {
                const s16x8 kf0 = *reinterpret_cast<const s16x8*>(
                    &K_lds[(n * 16 + l15) * 72 + quad * 8]);
                const s16x8 kf1 = *reinterpret_cast<const s16x8*>(
                    &K_lds[(n * 16 + l15) * 72 + 32 + quad * 8]);
                #pragma unroll
                for (int mi = 0; mi < 2; ++mi) {
                    f32x4 t = {};
                    t = __builtin_amdgcn_mfma_f32_16x16x32_bf16(kf0, qf[mi][0], t, 0, 0, 0);
                    t = __builtin_amdgcn_mfma_f32_16x16x32_bf16(kf1, qf[mi][1], t, 0, 0, 0);
                    st[mi][n] = t;
                }
            }

            // P = exp2(S^T) packed IN-REGISTER into K=16 A-frags.
            // Lane (l15,quad) holds keys kbase+n*16+quad*4+{0..3} of q-row
            // w0+mi*16+l15 == A[m=l15][k=quad*4+j] for chunk n. 2 cvt_pk
            // per frag; causal mask zeroes the f32 before packing.
            const bool diag = (kbase + 63 > w0);
            u16x4 pa[2][4];
            #pragma unroll
            for (int mi = 0; mi < 2; ++mi) {
                const int qr = w0 + mi * 16 + l15;
                #pragma unroll
                for (int n = 0; n < 4; ++n) {
                    const int kb = kbase + n * 16 + quad * 4;
                    float e0 = exp2f(st[mi][n][0]);
                    float e1 = exp2f(st[mi][n][1]);
                    float e2 = exp2f(st[mi][n][2]);
                    float e3 = exp2f(st[mi][n][3]);
                    if (diag) {
                        if (kb + 0 > qr) e0 = 0.0f;
                        if (kb + 1 > qr) e1 = 0.0f;
                        if (kb + 2 > qr) e2 = 0.0f;
                        if (kb + 3 > qr) e3 = 0.0f;
                    }
                    u32x2 w; w.x = cvtpk(e0, e1); w.y = cvtpk(e2, e3);
                    pa[mi][n] = __builtin_bit_cast(u16x4, w);
                }
            }

            // O += P V ; rowsum += P * ones. K=16 MFMAs; B-frags are b64
            // V_lds reads: B[n=f=n4*16+l15][k=quad*4+j] of key-chunk n.
            #pragma unroll
            for (int n = 0; n < 4; ++n) {
                #pragma unroll
                for (int mi = 0; mi < 2; ++mi)
                    mfma16(osum[mi], pa[mi][n], ones4);
                #pragma unroll
                for (int n4 = 0; n4 < 4; ++n4) {
                    const u16x4 vb = *reinterpret_cast<const u16x4*>(
                        &V_lds[(n4 * 16 + l15) * 72 + n * 16 + quad * 4]);
                    #pragma unroll
                    for (int mi = 0; mi < 2; ++mi)
                        mfma16(o[mi][n4], pa[mi][n], vb);
                }
            }
        }
    }

    // Epilogue. C/D layout: row = quad*4 + r, col = l15 (same for K=16).
    #pragma unroll
    for (int mi = 0; mi < 2; ++mi)
        #pragma unroll
        for (int r = 0; r < 4; ++r) {
            const float inv = 1.0f / osum[mi][r];
            const size_t rowO = (size_t)(b * T_ + w0 + mi * 16 + quad * 4 + r) * D_ + h * HD_;
            #pragma unroll
            for (int n4 = 0; n4 < 4; ++n4)
                out[rowO + n4 * 16 + l15] = f2bf(o[mi][n4][r] * inv);
        }
}

// ---------------------------------------------------------------------------
extern "C" void kernel_launch(void* const* d_in, const int* in_sizes, int n_in,
                              void* d_out, int out_size, void* d_ws, size_t ws_size,
                              hipStream_t stream)
{
    const float* x     = (const float*)d_in[0];  // [B,T,D]  fp32
    const float* Wqkv  = (const float*)d_in[1];  // [3D,D]   fp32
    const float* Wproj = (const float*)d_in[2];  // [D,D]    fp32
    const float* bproj = (const float*)d_in[3];  // [D]      fp32
    float* out = (float*)d_out;                  // [B,T,D]  fp32

    const int M = B_ * T_;
    const float cs = 0.18033688011f;             // (1/sqrt(64)) * log2(e)

    // Workspace (bf16 = u16). Total 88 MB, no aliasing.
    u16* xb    = (u16*)d_ws;                              // [M, D]       16 MB
    u16* wqkvb = xb    + (size_t)M * D_;                  // [3D, D]       6 MB
    u16* wprob = wqkvb + (size_t)THREE_D * D_;            // [D, D]        2 MB
    u16* qk    = wprob + (size_t)D_ * D_;                 // [M, 2D]      32 MB
    u16* vtb   = qk    + (size_t)M * TWO_D;               // [B*H*64, T]  16 MB
    u16* attn  = vtb   + (size_t)B_ * H_ * HD_ * T_;      // [M, D]       16 MB

    // 0) fp32 -> bf16 converts
    {
        int n;
        n = M * D_;
        cvt_f32_bf16<<<dim3((n / 4 + 255) / 256), 256, 0, stream>>>(x, xb, n);
        n = THREE_D * D_;
        cvt_f32_bf16<<<dim3((n / 4 + 255) / 256), 256, 0, stream>>>(Wqkv, wqkvb, n);
        n = D_ * D_;
        cvt_f32_bf16<<<dim3((n / 4 + 255) / 256), 256, 0, stream>>>(Wproj, wprob, n);
    }

    // 1) qkv GEMM: Q (scaled by cs) and K -> qk[M,2D]; V -> vt transposed
    gemm_bt128<1><<<dim3((M / 128) * (THREE_D / 128)), 256, 0, stream>>>(
        xb, wqkvb, qk, nullptr, M, THREE_D, D_, D_, D_, TWO_D, cs, vtb);

    // 2) causal flash attention (bf16 out)
    flash_attn9<<<dim3(B_ * H_ * (T_ / 128)), 256, 0, stream>>>(qk, vtb, attn);

    // 3) out = attn @ Wproj^T + bproj   (fp32 out)
    gemm_bt128<0><<<dim3((M / 128) * (D_ / 128)), 256, 0, stream>>>(
        attn, wprob, out, bproj, M, D_, D_, D_, D_, D_, 1.0f, nullptr);
}